// Round 4
// baseline (637.932 us; speedup 1.0000x reference)
//
#include <hip/hip_runtime.h>

typedef unsigned short u16;
typedef __attribute__((ext_vector_type(8))) short short8;
typedef __attribute__((ext_vector_type(4))) float f32x4;
typedef __attribute__((ext_vector_type(8))) u16 u16x8;

#define NROWS 32768
#define NCODES 8192
#define DIM 512
#define KT 16                     // 512 / 32

// GEMM geometry: 512 thr (8 waves 4x2), BM=256, BN=256, BK=64, dbuf LDS
#define BM 256
#define BN 256
#define NSPLIT 8
#define NT (NCODES / NSPLIT / BN)   // 4 col tiles per block
#define NU (NT * 8)                 // 32 stage-units (BK=64 each)

// workspace byte offsets
#define WB_ZH  ((size_t)0)                                // bf16 z, fragment order
#define WB_EH  (WB_ZH + (size_t)NROWS * DIM * 2)          // bf16 emb
#define WB_TE  (WB_EH + (size_t)NCODES * DIM * 2)         // fp32 ||e||^2
#define WB_K4  (WB_TE + (size_t)NCODES * 4)               // [NSPLIT][NROWS] int4 top4 keys
#define WB_SSQ (WB_K4 + (size_t)NSPLIT * NROWS * 16)      // [NROWS] fp32 row ssq
#define WB_NEED (WB_SSQ + (size_t)NROWS * 4 + 64)

__device__ __forceinline__ u16 f2bf(float x) {
  unsigned u = __float_as_uint(x);
  u += 0x7FFFu + ((u >> 16) & 1u);   // RNE; inputs finite
  return (u16)(u >> 16);
}
__device__ __forceinline__ void gld16(const void* g, void* l) {
  __builtin_amdgcn_global_load_lds(
      (const __attribute__((address_space(1))) void*)g,
      (__attribute__((address_space(3))) void*)l, 16, 0, 0);
}

// ---------------------------------------------------------------- row norms
__global__ void vq_rownorm(const float* __restrict__ x, float* __restrict__ out,
                           int nrows) {
  int gid  = blockIdx.x * blockDim.x + threadIdx.x;
  int w    = gid >> 6;
  int lane = gid & 63;
  if (w >= nrows) return;
  const float4* row = (const float4*)(x + (size_t)w * DIM);
  float4 a = row[lane];
  float4 b = row[lane + 64];
  float s = a.x * a.x + a.y * a.y + a.z * a.z + a.w * a.w
          + b.x * b.x + b.y * b.y + b.z * b.z + b.w * b.w;
#pragma unroll
  for (int off = 32; off > 0; off >>= 1) s += __shfl_down(s, off);
  if (lane == 0) out[w] = s;
}

// -------------------------------------------- fp32 -> bf16 fragment chunks
// chunk layout: [g (16-row group)][kt][lane][8 bf16], lane = kgrp*16 + row%16
__global__ void vq_tobf16(const float* __restrict__ x, u16* __restrict__ hi,
                          int nwaves) {
  int W = blockIdx.x * (blockDim.x >> 6) + (threadIdx.x >> 6);
  if (W >= nwaves) return;
  int lane = threadIdx.x & 63;
  int g = W >> 4, kt = W & (KT - 1);
  int row = g * 16 + (lane & 15);
  int k0  = kt * 32 + (lane >> 4) * 8;
  const float* src = x + (size_t)row * DIM + k0;
  f32x4 a = *(const f32x4*)src;
  f32x4 b = *(const f32x4*)(src + 4);
  float v[8] = {a[0], a[1], a[2], a[3], b[0], b[1], b[2], b[3]};
  u16x8 h;
#pragma unroll
  for (int j = 0; j < 8; ++j) h[j] = f2bf(v[j]);
  *(u16x8*)(hi + ((size_t)W * 64 + lane) * 8) = h;
}

// -------------- 1-pass bf16 MFMA ranking, 8-phase counted-vmcnt pipeline
// key = trunc((te - 2*dot)*2048)*8192 + col  (monotone lex in (d-bucket, col))
__global__ __launch_bounds__(512, 2) void vq_mfma_top4(
    const u16* __restrict__ zh, const u16* __restrict__ eh,
    const float* __restrict__ te, int4* __restrict__ k4) {
  // A: 2 bufs x 32 chunks x 1KB = 64KB | B: same = 64KB  (chunk = 512 u16)
  __shared__ __align__(16) u16 lds[65536];

  const int tid  = threadIdx.x;
  const int w    = tid >> 6;
  const int lane = tid & 63;
  const int wr   = w >> 1;          // 0..3 : rows wr*64..+63
  const int wc   = w & 1;           // 0..1 : cols wc*128..+127
  const int l15  = lane & 15;
  const int bx   = blockIdx.x;
  const int split = blockIdx.y;
  const int cbg  = split * (NT * 16);          // codebook col-group base

  const size_t laneo = (size_t)lane * 8;
  const u16* Asrc = zh + ((size_t)bx * 16) * (KT * 512);
  const u16* Bsrc = eh + ((size_t)cbg) * (KT * 512);

  f32x4 acc[4][8];
  int k1[16], k2[16];
#pragma unroll
  for (int s = 0; s < 16; ++s) { k1[s] = 0x7fffffff; k2[s] = 0x7fffffff; }

  // stage one unit (BK=64: A 32 chunks + B 32 chunks; wave w does 8)
  auto stage = [&](int u, int db) {
    const int nt = u >> 3, uks = u & 7;
#pragma unroll
    for (int j = 0; j < 8; ++j) {
      const int c = w * 8 + j;
      if (c < 32) {
        const int g = c >> 1, kto = c & 1;
        gld16(Asrc + ((size_t)g * KT + uks * 2 + kto) * 512 + laneo,
              lds + db * 16384 + c * 512);
      } else {
        const int cc = c - 32, cg = cc >> 1, kto = cc & 1;
        gld16(Bsrc + ((size_t)(nt * 16 + cg) * KT + uks * 2 + kto) * 512 + laneo,
              lds + 32768 + db * 16384 + cc * 512);
      }
    }
  };

  stage(0, 0);

#pragma unroll 2
  for (int u = 0; u < NU; ++u) {
    const int db = u & 1;
    // issue next unit's loads FIRST, then counted wait drains only unit u's 8
    if (u + 1 < NU) {
      stage(u + 1, db ^ 1);
      asm volatile("s_waitcnt vmcnt(8)" ::: "memory");
    } else {
      asm volatile("s_waitcnt vmcnt(0)" ::: "memory");
    }
    __builtin_amdgcn_s_barrier();

    if ((u & 7) == 0) {
#pragma unroll
      for (int m = 0; m < 4; ++m)
#pragma unroll
        for (int n = 0; n < 8; ++n) acc[m][n] = (f32x4){0.f, 0.f, 0.f, 0.f};
    }

    const u16* Ab = lds + db * 16384;
    const u16* Bb = lds + 32768 + db * 16384;
    short8 a[4], b[4];
#pragma unroll
    for (int ph = 0; ph < 4; ++ph) {
      const int kss = ph >> 1, nh = ph & 1;
      if (nh == 0) {
#pragma unroll
        for (int m = 0; m < 4; ++m)
          a[m] = *(const short8*)(Ab + ((wr * 4 + m) * 2 + kss) * 512 + lane * 8);
      }
#pragma unroll
      for (int n = 0; n < 4; ++n)
        b[n] = *(const short8*)(Bb + ((wc * 8 + nh * 4 + n) * 2 + kss) * 512 + lane * 8);
      __builtin_amdgcn_s_setprio(1);
#pragma unroll
      for (int n = 0; n < 4; ++n)
#pragma unroll
        for (int m = 0; m < 4; ++m)
          acc[m][nh * 4 + n] =
              __builtin_amdgcn_mfma_f32_16x16x32_bf16(a[m], b[n], acc[m][nh * 4 + n], 0, 0, 0);
      __builtin_amdgcn_s_setprio(0);
      __builtin_amdgcn_s_barrier();
    }

    // end of a col-tile: fold acc into per-cell top2 keys (branchless)
    if ((u & 7) == 7) {
      const int nt = u >> 3;
      const int colt0 = split * (NT * 256) + nt * 256 + wc * 128 + l15;
#pragma unroll
      for (int n = 0; n < 8; ++n) {
        const int col = colt0 + n * 16;
        const float tv2 = te[col] * 2048.0f;
#pragma unroll
        for (int m = 0; m < 4; ++m)
#pragma unroll
          for (int q = 0; q < 4; ++q) {
            const float kf = fmaf(acc[m][n][q], -4096.0f, tv2);
            const int key = (int)((unsigned)(int)kf << 13) + col;
            const int s = m * 4 + q;
            const int hi = max(k1[s], key);
            k1[s] = min(k1[s], key);
            k2[s] = min(k2[s], hi);
          }
      }
    }
  }

  // dump per-thread top2s; per-row top4 scan (LDS free after main loop)
  __builtin_amdgcn_s_barrier();
  int* di = (int*)lds;   // [256 rows][64 keys] = 64KB
#pragma unroll
  for (int m = 0; m < 4; ++m)
#pragma unroll
    for (int q = 0; q < 4; ++q) {
      const int s = m * 4 + q;
      const int r = wr * 64 + m * 16 + (lane >> 4) * 4 + q;
      const int base = r * 64 + wc * 32 + l15 * 2;
      di[base] = k1[s];
      di[base + 1] = k2[s];
    }
  __builtin_amdgcn_s_barrier();
  if (tid < 256) {
    int t0 = 0x7fffffff, t1 = 0x7fffffff, t2 = 0x7fffffff, t3 = 0x7fffffff;
#pragma unroll
    for (int j = 0; j < 64; ++j) {
      const int jj = (j + tid) & 63;   // rotated scan: 2-way banks (free)
      int k = di[tid * 64 + jj];
      int x;
      x = min(t0, k); k = max(t0, k); t0 = x;
      x = min(t1, k); k = max(t1, k); t1 = x;
      x = min(t2, k); k = max(t2, k); t2 = x;
      t3 = min(t3, k);
    }
    k4[(size_t)split * NROWS + bx * 256 + tid] = make_int4(t0, t1, t2, t3);
  }
}

// ------------- merge 8x4 keys -> global top8, exact fp32 rescore, output
__global__ void vq_rescore8(const float* __restrict__ z, const float* __restrict__ emb,
                            const float* __restrict__ te, const int4* __restrict__ k4,
                            float* __restrict__ out, float* __restrict__ rowssq) {
  const int row  = (blockIdx.x * blockDim.x + threadIdx.x) >> 6;
  const int lane = threadIdx.x & 63;
  if (row >= NROWS) return;

  int t[8];
#pragma unroll
  for (int j = 0; j < 8; ++j) t[j] = 0x7fffffff;
#pragma unroll
  for (int s = 0; s < NSPLIT; ++s) {
    const int4 kk = k4[(size_t)s * NROWS + row];
    int c[4] = {kk.x, kk.y, kk.z, kk.w};
#pragma unroll
    for (int u = 0; u < 4; ++u) {
      int k = c[u];
#pragma unroll
      for (int j = 0; j < 8; ++j) {
        const int lo = min(t[j], k);
        k = max(t[j], k);
        t[j] = lo;
      }
    }
  }

  int idx[8];
#pragma unroll
  for (int c = 0; c < 8; ++c) idx[c] = t[c] & 8191;

  const f32x4* zr = (const f32x4*)(z + (size_t)row * DIM);
  const f32x4 za = zr[lane], zb = zr[lane + 64];

  f32x4 ea[8], eb[8];
#pragma unroll
  for (int c = 0; c < 8; ++c) {
    const f32x4* er = (const f32x4*)(emb + (size_t)idx[c] * DIM);
    ea[c] = er[lane];
    eb[c] = er[lane + 64];
  }

  float sp = za[0] * za[0] + za[1] * za[1] + za[2] * za[2] + za[3] * za[3]
           + zb[0] * zb[0] + zb[1] * zb[1] + zb[2] * zb[2] + zb[3] * zb[3];
  float p[8];
#pragma unroll
  for (int c = 0; c < 8; ++c)
    p[c] = za[0] * ea[c][0] + za[1] * ea[c][1] + za[2] * ea[c][2] + za[3] * ea[c][3]
         + zb[0] * eb[c][0] + zb[1] * eb[c][1] + zb[2] * eb[c][2] + zb[3] * eb[c][3];

#pragma unroll
  for (int off = 32; off > 0; off >>= 1) {
    sp += __shfl_down(sp, off);
#pragma unroll
    for (int c = 0; c < 8; ++c) p[c] += __shfl_down(p[c], off);
  }
  sp = __shfl(sp, 0);
#pragma unroll
  for (int c = 0; c < 8; ++c) p[c] = __shfl(p[c], 0);

  float bd = (sp + te[idx[0]]) - 2.0f * p[0];
  int   bi = idx[0];
  f32x4 ga = ea[0], gb = eb[0];
#pragma unroll
  for (int c = 1; c < 8; ++c) {
    const float d = (sp + te[idx[c]]) - 2.0f * p[c];
    const bool better = (d < bd) || (d == bd && idx[c] < bi);
    if (better) { bd = d; bi = idx[c]; ga = ea[c]; gb = eb[c]; }
  }

  float* orow = out + 1 + (size_t)row * DIM;
  float lsum = 0.f;
#pragma unroll
  for (int j = 0; j < 4; ++j) {
    const float dv = ga[j] - za[j];
    orow[4 * lane + j] = za[j] + dv;
    lsum += dv * dv;
    const float dw = gb[j] - zb[j];
    orow[256 + 4 * lane + j] = zb[j] + dw;
    lsum += dw * dw;
  }
#pragma unroll
  for (int off = 32; off > 0; off >>= 1) lsum += __shfl_down(lsum, off);
  if (lane == 0) {
    rowssq[row] = lsum;
    out[1 + (size_t)NROWS * DIM + row] = (float)bi;
  }
}

// ----------------------------- single-block loss reduction (no atomics)
__global__ void vq_finalize(const float* __restrict__ rowssq, float* __restrict__ out) {
  __shared__ float red[16];
  float s = 0.f;
  for (int i = threadIdx.x; i < NROWS; i += 1024) s += rowssq[i];
#pragma unroll
  for (int off = 32; off > 0; off >>= 1) s += __shfl_down(s, off);
  if ((threadIdx.x & 63) == 0) red[threadIdx.x >> 6] = s;
  __syncthreads();
  if (threadIdx.x < 64) {
    float v = (threadIdx.x < 16) ? red[threadIdx.x] : 0.f;
#pragma unroll
    for (int off = 32; off > 0; off >>= 1) v += __shfl_down(v, off);
    if (threadIdx.x == 0) {
      const float m = v / 16777216.0f;   // mean over N*D = 2^24 (exact)
      out[0] = m + m;                    // (1 + BETA) * m
    }
  }
}

// ==========================================================================
extern "C" void kernel_launch(void* const* d_in, const int* in_sizes, int n_in,
                              void* d_out, int out_size, void* d_ws, size_t ws_size,
                              hipStream_t stream) {
  const float* z   = (const float*)d_in[0];
  const float* emb = (const float*)d_in[1];
  float* out = (float*)d_out;
  char*  ws  = (char*)d_ws;

  u16*   zh  = (u16*)(ws + WB_ZH);
  u16*   eh  = (u16*)(ws + WB_EH);
  float* te  = (float*)(ws + WB_TE);
  int4*  k4  = (int4*)(ws + WB_K4);
  float* ssq = (float*)(ws + WB_SSQ);

  vq_tobf16<<<(NROWS / 16) * KT / 4, 256, 0, stream>>>(z, zh, (NROWS / 16) * KT);
  vq_tobf16<<<(NCODES / 16) * KT / 4, 256, 0, stream>>>(emb, eh, (NCODES / 16) * KT);
  vq_rownorm<<<NCODES / 4, 256, 0, stream>>>(emb, te, NCODES);

  vq_mfma_top4<<<dim3(NROWS / BM, NSPLIT), 512, 0, stream>>>(zh, eh, te, k4);

  vq_rescore8<<<NROWS / 4, 256, 0, stream>>>(z, emb, te, k4, out, ssq);
  vq_finalize<<<1, 1024, 0, stream>>>(ssq, out);
}

// Round 7
// 562.525 us; speedup vs baseline: 1.1341x; 1.1341x over previous
//
#include <hip/hip_runtime.h>

typedef unsigned short u16;
typedef __attribute__((ext_vector_type(8))) short short8;
typedef __attribute__((ext_vector_type(4))) float f32x4;
typedef __attribute__((ext_vector_type(8))) u16 u16x8;

#define NROWS 32768
#define NCODES 8192
#define DIM 512
#define KT 16                       // 512 / 32

// GEMM geometry: 512 thr (8 waves, 4M x 2N), BM=256, BN=256, BK=32, ring-4 LDS
#define BM 256
#define BN 256
#define NSPLIT 4
#define NT (NCODES / NSPLIT / BN)   // 8 col tiles per block
#define NU (NT * KT)                // 128 K-units per block

// workspace byte offsets
#define WB_ZH  ((size_t)0)                                // bf16 z, fragment order
#define WB_EH  (WB_ZH + (size_t)NROWS * DIM * 2)          // bf16 emb
#define WB_K4  (WB_EH + (size_t)NCODES * DIM * 2)         // [NSPLIT][NROWS] int4 top4 keys
#define WB_SSQ (WB_K4 + (size_t)NSPLIT * NROWS * 16)      // [NROWS] fp32 row ssq

__device__ __forceinline__ u16 f2bf(float x) {
  unsigned u = __float_as_uint(x);
  u += 0x7FFFu + ((u >> 16) & 1u);   // RNE; inputs finite
  return (u16)(u >> 16);
}
__device__ __forceinline__ void gld16(const void* g, void* l) {
  __builtin_amdgcn_global_load_lds(
      (const __attribute__((address_space(1))) void*)g,
      (__attribute__((address_space(3))) void*)l, 16, 0, 0);
}

// -------------------------------------------- fp32 -> bf16 fragment chunks
// chunk layout: [g (16-row group)][kt][lane][8 bf16], lane = kgrp*16 + row%16
__global__ void vq_tobf16(const float* __restrict__ x, u16* __restrict__ hi,
                          int nwaves) {
  int W = blockIdx.x * (blockDim.x >> 6) + (threadIdx.x >> 6);
  if (W >= nwaves) return;
  int lane = threadIdx.x & 63;
  int g = W >> 4, kt = W & (KT - 1);
  int row = g * 16 + (lane & 15);
  int k0  = kt * 32 + (lane >> 4) * 8;
  const float* src = x + (size_t)row * DIM + k0;
  f32x4 a = *(const f32x4*)src;
  f32x4 b = *(const f32x4*)(src + 4);
  float v[8] = {a[0], a[1], a[2], a[3], b[0], b[1], b[2], b[3]};
  u16x8 h;
#pragma unroll
  for (int j = 0; j < 8; ++j) h[j] = f2bf(v[j]);
  *(u16x8*)(hi + ((size_t)W * 64 + lane) * 8) = h;
}

// ---------------- 1-pass bf16 MFMA ranking, ring-4 counted-vmcnt pipeline
// ranking key = trunc(16384 - 4096*dot)*8192 + col  (||e|| const -> te-free;
// monotone lex in (approx-d bucket, col); exact rescore fixes boundaries)
__global__ __launch_bounds__(512, 2) void vq_mfma_top4(
    const u16* __restrict__ zh, const u16* __restrict__ eh,
    int4* __restrict__ k4) {
  // ring of 4 bufs x (A 16KB | B 16KB) = 128 KiB
  __shared__ __align__(16) u16 lds[65536];

  const int tid   = threadIdx.x;
  const int w     = tid >> 6;
  const int lane  = tid & 63;
  const int wm    = w >> 1;          // 0..3 : rows wm*64..+63
  const int wn    = w & 1;           // 0..1 : cols wn*128..+127
  const int l15   = lane & 15;
  const int bx    = blockIdx.x;
  const int split = blockIdx.y;

  const u16* Asrc = zh + (size_t)(bx * 16) * (KT * 512);
  const u16* Bsrc = eh + (size_t)(split * (NT * 16)) * (KT * 512);
  const int laneo = lane * 8;

  f32x4 acc[4][8];
  int k1[16], k2[16];
#pragma unroll
  for (int s = 0; s < 16; ++s) { k1[s] = 0x7fffffff; k2[s] = 0x7fffffff; }

  // stage unit u (nt = u>>4, kt = u&15) into ring slot r: 4 gld16 per thread,
  // wave w stages chunks {w, w+8} of A and of B (dest wave-uniform + lane*16B)
  auto stage = [&](int u, int r) {
    const int nt = u >> 4, kt = u & 15;
    u16* dstA = (u16*)lds + r * 16384;
    u16* dstB = dstA + 8192;
#pragma unroll
    for (int j = 0; j < 2; ++j) {
      const int g = w + j * 8;
      gld16(Asrc + ((size_t)(g * KT + kt)) * 512 + laneo, dstA + g * 512);
      gld16(Bsrc + ((size_t)((nt * 16 + g) * KT + kt)) * 512 + laneo,
            dstB + g * 512);
    }
  };

  // prologue: 3 units in flight, wait for unit 0 (12 -> 8 outstanding)
  stage(0, 0);
  stage(1, 1);
  stage(2, 2);
  asm volatile("s_waitcnt vmcnt(8)" ::: "memory");
  asm volatile("s_barrier" ::: "memory");

#pragma unroll 4
  for (int u = 0; u < NU; ++u) {
    if (u + 3 < NU) stage(u + 3, (u + 3) & 3);

    if ((u & 15) == 0) {
#pragma unroll
      for (int m = 0; m < 4; ++m)
#pragma unroll
        for (int n = 0; n < 8; ++n) acc[m][n] = (f32x4){0.f, 0.f, 0.f, 0.f};
    }

    const u16* bufA = (const u16*)lds + (u & 3) * 16384;
    const u16* bufB = bufA + 8192;
    short8 a[4];
#pragma unroll
    for (int m = 0; m < 4; ++m)
      a[m] = *(const short8*)(bufA + (wm * 4 + m) * 512 + laneo);
    __builtin_amdgcn_s_setprio(1);
#pragma unroll
    for (int n = 0; n < 8; ++n) {
      const short8 b = *(const short8*)(bufB + (wn * 8 + n) * 512 + laneo);
#pragma unroll
      for (int m = 0; m < 4; ++m)
        acc[m][n] = __builtin_amdgcn_mfma_f32_16x16x32_bf16(a[m], b, acc[m][n], 0, 0, 0);
    }
    __builtin_amdgcn_s_setprio(0);

    // end of col-tile: fold acc into per-cell top2 keys (branchless, te-free)
    if ((u & 15) == 15) {
      const int nt = u >> 4;
      const int col0 = split * (NT * 256) + nt * 256 + wn * 128 + l15;
#pragma unroll
      for (int n = 0; n < 8; ++n) {
        const int col = col0 + n * 16;
#pragma unroll
        for (int m = 0; m < 4; ++m)
#pragma unroll
          for (int q = 0; q < 4; ++q) {
            const float kf = fmaf(acc[m][n][q], -4096.0f, 16384.0f);
            const int key = ((int)kf << 13) + col;
            const int s = m * 4 + q;
            const int hi = max(k1[s], key);
            k1[s] = min(k1[s], key);
            k2[s] = min(k2[s], hi);
          }
      }
    }

    // counted drain: keep 2 staged units in flight across the barrier
    if (u + 3 < NU) {
      asm volatile("s_waitcnt vmcnt(8)" ::: "memory");
    } else if (u + 2 < NU) {
      asm volatile("s_waitcnt vmcnt(4)" ::: "memory");
    } else {
      asm volatile("s_waitcnt vmcnt(0)" ::: "memory");
    }
    asm volatile("s_barrier" ::: "memory");
  }

  // dump per-thread top2s; per-row top4 scan (LDS reused: [256 rows][64 keys])
  __syncthreads();
  int* di = (int*)lds;
#pragma unroll
  for (int m = 0; m < 4; ++m)
#pragma unroll
    for (int q = 0; q < 4; ++q) {
      const int s = m * 4 + q;
      const int r = wm * 64 + m * 16 + (lane >> 4) * 4 + q;
      const int base = r * 64 + wn * 32 + l15 * 2;
      di[base] = k1[s];
      di[base + 1] = k2[s];
    }
  __syncthreads();
  if (tid < 256) {
    int t0 = 0x7fffffff, t1 = 0x7fffffff, t2 = 0x7fffffff, t3 = 0x7fffffff;
#pragma unroll
    for (int j = 0; j < 64; ++j) {
      const int jj = (j + tid) & 63;   // rotated scan keeps banks spread
      int k = di[tid * 64 + jj];
      int x;
      x = min(t0, k); k = max(t0, k); t0 = x;
      x = min(t1, k); k = max(t1, k); t1 = x;
      x = min(t2, k); k = max(t2, k); t2 = x;
      t3 = min(t3, k);
    }
    k4[(size_t)split * NROWS + bx * 256 + tid] = make_int4(t0, t1, t2, t3);
  }
}

// --- merge 4x4 keys -> global top8, exact fp32 rescore (inline ||e||^2), out
__global__ void vq_rescore8(const float* __restrict__ z, const float* __restrict__ emb,
                            const int4* __restrict__ k4,
                            float* __restrict__ out, float* __restrict__ rowssq) {
  const int row  = (blockIdx.x * blockDim.x + threadIdx.x) >> 6;
  const int lane = threadIdx.x & 63;
  if (row >= NROWS) return;

  int t[8];
#pragma unroll
  for (int j = 0; j < 8; ++j) t[j] = 0x7fffffff;
#pragma unroll
  for (int s = 0; s < NSPLIT; ++s) {
    const int4 kk = k4[(size_t)s * NROWS + row];
    int c[4] = {kk.x, kk.y, kk.z, kk.w};
#pragma unroll
    for (int u = 0; u < 4; ++u) {
      int k = c[u];
#pragma unroll
      for (int j = 0; j < 8; ++j) {
        const int lo = min(t[j], k);
        k = max(t[j], k);
        t[j] = lo;
      }
    }
  }

  int idx[8];
#pragma unroll
  for (int c = 0; c < 8; ++c) idx[c] = t[c] & 8191;

  const f32x4* zr = (const f32x4*)(z + (size_t)row * DIM);
  const f32x4 za = zr[lane], zb = zr[lane + 64];

  f32x4 ea[8], eb[8];
#pragma unroll
  for (int c = 0; c < 8; ++c) {
    const f32x4* er = (const f32x4*)(emb + (size_t)idx[c] * DIM);
    ea[c] = er[lane];
    eb[c] = er[lane + 64];
  }

  float sp = za[0] * za[0] + za[1] * za[1] + za[2] * za[2] + za[3] * za[3]
           + zb[0] * zb[0] + zb[1] * zb[1] + zb[2] * zb[2] + zb[3] * zb[3];
  float p[8], qn[8];
#pragma unroll
  for (int c = 0; c < 8; ++c) {
    p[c]  = za[0] * ea[c][0] + za[1] * ea[c][1] + za[2] * ea[c][2] + za[3] * ea[c][3]
          + zb[0] * eb[c][0] + zb[1] * eb[c][1] + zb[2] * eb[c][2] + zb[3] * eb[c][3];
    qn[c] = ea[c][0] * ea[c][0] + ea[c][1] * ea[c][1] + ea[c][2] * ea[c][2] + ea[c][3] * ea[c][3]
          + eb[c][0] * eb[c][0] + eb[c][1] * eb[c][1] + eb[c][2] * eb[c][2] + eb[c][3] * eb[c][3];
  }

#pragma unroll
  for (int off = 32; off > 0; off >>= 1) {
    sp += __shfl_down(sp, off);
#pragma unroll
    for (int c = 0; c < 8; ++c) {
      p[c]  += __shfl_down(p[c], off);
      qn[c] += __shfl_down(qn[c], off);
    }
  }
  sp = __shfl(sp, 0);
#pragma unroll
  for (int c = 0; c < 8; ++c) {
    p[c]  = __shfl(p[c], 0);
    qn[c] = __shfl(qn[c], 0);
  }

  float bd = (sp + qn[0]) - 2.0f * p[0];
  int   bi = idx[0];
  f32x4 ga = ea[0], gb = eb[0];
#pragma unroll
  for (int c = 1; c < 8; ++c) {
    const float d = (sp + qn[c]) - 2.0f * p[c];
    const bool better = (d < bd) || (d == bd && idx[c] < bi);
    if (better) { bd = d; bi = idx[c]; ga = ea[c]; gb = eb[c]; }
  }

  float* orow = out + 1 + (size_t)row * DIM;
  float lsum = 0.f;
#pragma unroll
  for (int j = 0; j < 4; ++j) {
    const float dv = ga[j] - za[j];
    orow[4 * lane + j] = za[j] + dv;
    lsum += dv * dv;
    const float dw = gb[j] - zb[j];
    orow[256 + 4 * lane + j] = zb[j] + dw;
    lsum += dw * dw;
  }
#pragma unroll
  for (int off = 32; off > 0; off >>= 1) lsum += __shfl_down(lsum, off);
  if (lane == 0) {
    rowssq[row] = lsum;
    out[1 + (size_t)NROWS * DIM + row] = (float)bi;
  }
}

// ----------------------------- single-block loss reduction (no atomics)
__global__ void vq_finalize(const float* __restrict__ rowssq, float* __restrict__ out) {
  __shared__ float red[16];
  float s = 0.f;
  for (int i = threadIdx.x; i < NROWS; i += 1024) s += rowssq[i];
#pragma unroll
  for (int off = 32; off > 0; off >>= 1) s += __shfl_down(s, off);
  if ((threadIdx.x & 63) == 0) red[threadIdx.x >> 6] = s;
  __syncthreads();
  if (threadIdx.x < 64) {
    float v = (threadIdx.x < 16) ? red[threadIdx.x] : 0.f;
#pragma unroll
    for (int off = 32; off > 0; off >>= 1) v += __shfl_down(v, off);
    if (threadIdx.x == 0) {
      const float m = v / 16777216.0f;   // mean over N*D = 2^24 (exact)
      out[0] = m + m;                    // (1 + BETA) * m
    }
  }
}

// ==========================================================================
extern "C" void kernel_launch(void* const* d_in, const int* in_sizes, int n_in,
                              void* d_out, int out_size, void* d_ws, size_t ws_size,
                              hipStream_t stream) {
  const float* z   = (const float*)d_in[0];
  const float* emb = (const float*)d_in[1];
  float* out = (float*)d_out;
  char*  ws  = (char*)d_ws;

  u16*   zh  = (u16*)(ws + WB_ZH);
  u16*   eh  = (u16*)(ws + WB_EH);
  int4*  k4  = (int4*)(ws + WB_K4);
  float* ssq = (float*)(ws + WB_SSQ);

  vq_tobf16<<<(NROWS / 16) * KT / 4, 256, 0, stream>>>(z, zh, (NROWS / 16) * KT);
  vq_tobf16<<<(NCODES / 16) * KT / 4, 256, 0, stream>>>(emb, eh, (NCODES / 16) * KT);

  vq_mfma_top4<<<dim3(NROWS / BM, NSPLIT), 512, 0, stream>>>(zh, eh, k4);

  vq_rescore8<<<NROWS / 4, 256, 0, stream>>>(z, emb, k4, out, ssq);
  vq_finalize<<<1, 1024, 0, stream>>>(ssq, out);
}